// Round 13
// baseline (159.908 us; speedup 1.0000x reference)
//
#include <hip/hip_runtime.h>
#include <math.h>

#define NB 16384
#define ND 512
#define NE 16
#define NH 2048
#define BM 256            // rows per tile
#define BN 256            // cols per tile
#define BK 64             // k per step
#define NCHU 8            // 256-col chunks
#define NPW 32            // partials per row (8 ch x 4 wn)
#define UCAP (NE * 64 * NCHU)   // unit pool capacity (rt up to 64: any skew safe)
#define GEMM_GRID 512
#define LN_EPS 1e-5f

typedef __attribute__((ext_vector_type(8))) short s8v;   // 8 bf16
typedef __attribute__((ext_vector_type(4))) float f4v;   // mfma acc

// ---- ws layout (bytes) ----
#define WS_W1T_OFF   ((size_t)0)
#define WS_W1T_BYTES ((size_t)NE * NH * ND * 2)           // 32 MiB
#define WS_XN_OFF    (WS_W1T_OFF + WS_W1T_BYTES)
#define WS_XN_BYTES  ((size_t)NB * ND * 2)                // 16 MiB
#define WS_XNS_OFF   (WS_XN_OFF + WS_XN_BYTES)
#define WS_XNS_BYTES ((size_t)NB * ND * 2)                // 16 MiB
#define WS_PART_OFF  (WS_XNS_OFF + WS_XNS_BYTES)
#define WS_PART_BYTES ((size_t)NB * NPW * 4)              // 2 MiB
#define WS_IDX_OFF   (WS_PART_OFF + WS_PART_BYTES)
#define WS_ROWOF_OFF (WS_IDX_OFF + (size_t)NB * 4)
#define WS_CNT_OFF   (WS_ROWOF_OFF + (size_t)NB * 4)
#define WS_ROWS_OFF  (WS_CNT_OFF + 256)

__device__ __forceinline__ unsigned short bf16_rne(float f) {
    unsigned u = __float_as_uint(f);
    unsigned r = (u + 0x7fffu + ((u >> 16) & 1u)) >> 16;
    return (unsigned short)r;
}

// ---------------- Kernel A: w1 [E][D][H] f32 -> w1t [E][H][D] bf16 --------
__global__ __launch_bounds__(256) void w1conv_kernel(
    const float* __restrict__ w1, unsigned short* __restrict__ w1t)
{
    int bid = blockIdx.x;
    int e = bid & 15;
    int rest = bid >> 4;
    int db = rest & 7;
    int hb = rest >> 3;
    int h = hb * 256 + threadIdx.x;

    const float* src = w1 + ((size_t)e * ND + db * 64) * NH + h;
    unsigned int u[32];
#pragma unroll
    for (int p = 0; p < 32; ++p) {
        float f0 = src[(size_t)(2 * p) * NH];
        float f1 = src[(size_t)(2 * p + 1) * NH];
        u[p] = (unsigned)bf16_rne(f0) | ((unsigned)bf16_rne(f1) << 16);
    }
    uint4* dst = reinterpret_cast<uint4*>(
        w1t + ((size_t)e * NH + h) * ND + db * 64);
#pragma unroll
    for (int p = 0; p < 8; ++p)
        dst[p] = make_uint4(u[4 * p], u[4 * p + 1], u[4 * p + 2], u[4 * p + 3]);
}

// ---------------- Kernel B: gate + softmax + argmax + LN + xn(bf16) -------
__global__ __launch_bounds__(256) void gate_ln_kernel(
    const float* __restrict__ z, const float* __restrict__ gw,
    const float* __restrict__ gb, const float* __restrict__ ln_s,
    const float* __restrict__ ln_b, unsigned short* __restrict__ xn,
    int* __restrict__ idx_ws, float* __restrict__ g_out)
{
    int wave = threadIdx.x >> 6;
    int lane = threadIdx.x & 63;
    int b = blockIdx.x * 4 + wave;
    int q = lane & 3, dg = lane >> 2;

    const float* zr = z + (size_t)b * ND;
    float4 zv[8];
#pragma unroll
    for (int i = 0; i < 8; ++i)
        zv[i] = *reinterpret_cast<const float4*>(zr + dg * 32 + i * 4);

    float sum = 0.f, ssq = 0.f;
    float ga[4] = {0.f, 0.f, 0.f, 0.f};
#pragma unroll
    for (int i = 0; i < 8; ++i) {
        float zs[4] = {zv[i].x, zv[i].y, zv[i].z, zv[i].w};
#pragma unroll
        for (int t = 0; t < 4; ++t) {
            int d = dg * 32 + i * 4 + t;
            float4 w4 = *reinterpret_cast<const float4*>(gw + (size_t)d * NE + q * 4);
            ga[0] = fmaf(zs[t], w4.x, ga[0]);
            ga[1] = fmaf(zs[t], w4.y, ga[1]);
            ga[2] = fmaf(zs[t], w4.z, ga[2]);
            ga[3] = fmaf(zs[t], w4.w, ga[3]);
            sum += zs[t];
            ssq = fmaf(zs[t], zs[t], ssq);
        }
    }
#pragma unroll
    for (int m = 4; m <= 32; m <<= 1) {
        sum += __shfl_xor(sum, m);
        ssq += __shfl_xor(ssq, m);
#pragma unroll
        for (int j = 0; j < 4; ++j) ga[j] += __shfl_xor(ga[j], m);
    }
#pragma unroll
    for (int j = 0; j < 4; ++j) ga[j] += gb[q * 4 + j];

    float mu = sum * (1.f / ND);
    float var = ssq * (1.f / ND) - mu * mu;
    float rstd = rsqrtf(var + LN_EPS);

    float lmax = fmaxf(fmaxf(ga[0], ga[1]), fmaxf(ga[2], ga[3]));
    lmax = fmaxf(lmax, __shfl_xor(lmax, 1));
    lmax = fmaxf(lmax, __shfl_xor(lmax, 2));
    float ge[4], lsum = 0.f;
#pragma unroll
    for (int j = 0; j < 4; ++j) { ge[j] = __expf(ga[j] - lmax); lsum += ge[j]; }
    lsum += __shfl_xor(lsum, 1);
    lsum += __shfl_xor(lsum, 2);
    float rden = 1.f / lsum;

    int li = 1000;
#pragma unroll
    for (int j = 3; j >= 0; --j) if (ga[j] == lmax) li = q * 4 + j;
    li = min(li, __shfl_xor(li, 1));
    li = min(li, __shfl_xor(li, 2));

    // g write: lane l<16 wants expert l = (l>>2)*4 + (l&3)
    float gv0 = ge[0] * rden, gv1 = ge[1] * rden;
    float gv2 = ge[2] * rden, gv3 = ge[3] * rden;
    int srcl = lane >> 2;
    float t0 = __shfl(gv0, srcl), t1 = __shfl(gv1, srcl);
    float t2 = __shfl(gv2, srcl), t3 = __shfl(gv3, srcl);
    float gval = (q == 0) ? t0 : (q == 1) ? t1 : (q == 2) ? t2 : t3;
    if (lane < NE) g_out[(size_t)b * NE + lane] = gval;

    // xn: lane writes d = dg*32 + q*8 .. +8 (16B)
    float4 xa, xc;
    if (q == 0)      { xa = zv[0]; xc = zv[1]; }
    else if (q == 1) { xa = zv[2]; xc = zv[3]; }
    else if (q == 2) { xa = zv[4]; xc = zv[5]; }
    else             { xa = zv[6]; xc = zv[7]; }
    int dofs = dg * 32 + q * 8;
    const float* ls = ln_s + (size_t)li * ND + dofs;
    const float* lb = ln_b + (size_t)li * ND + dofs;
    float4 s0 = *reinterpret_cast<const float4*>(ls);
    float4 s1 = *reinterpret_cast<const float4*>(ls + 4);
    float4 u0 = *reinterpret_cast<const float4*>(lb);
    float4 u1 = *reinterpret_cast<const float4*>(lb + 4);
    unsigned short xb[8];
    xb[0] = bf16_rne((xa.x - mu) * rstd * s0.x + u0.x);
    xb[1] = bf16_rne((xa.y - mu) * rstd * s0.y + u0.y);
    xb[2] = bf16_rne((xa.z - mu) * rstd * s0.z + u0.z);
    xb[3] = bf16_rne((xa.w - mu) * rstd * s0.w + u0.w);
    xb[4] = bf16_rne((xc.x - mu) * rstd * s1.x + u1.x);
    xb[5] = bf16_rne((xc.y - mu) * rstd * s1.y + u1.y);
    xb[6] = bf16_rne((xc.z - mu) * rstd * s1.z + u1.z);
    xb[7] = bf16_rne((xc.w - mu) * rstd * s1.w + u1.w);
    *reinterpret_cast<s8v*>(xn + (size_t)b * ND + dofs) =
        *reinterpret_cast<s8v*>(xb);

    if (lane == 0) idx_ws[b] = li;
}

// ---------------- Kernel C: bucket build, 4-wave two-pass -----------------
__global__ __launch_bounds__(256) void bucket_kernel(
    const int* __restrict__ idx_ws, int* __restrict__ counts,
    int* __restrict__ rows)
{
    __shared__ int qc[4];
    int e = blockIdx.x;
    int tid = threadIdx.x, w = tid >> 6, lane = tid & 63;
    const int4* p = reinterpret_cast<const int4*>(idx_ws) + (size_t)w * 1024;

    int c = 0;
#pragma unroll 4
    for (int it = 0; it < 16; ++it) {
        int4 v = p[it * 64 + lane];
        c += (v.x == e) + (v.y == e) + (v.z == e) + (v.w == e);
    }
#pragma unroll
    for (int m = 1; m < 64; m <<= 1) c += __shfl_xor(c, m);
    if (lane == 0) qc[w] = c;
    __syncthreads();

    int base = 0;
    for (int j = 0; j < w; ++j) base += qc[j];
    unsigned long long below = (lane == 0) ? 0ull : ((~0ull) >> (64 - lane));
    int* re = rows + (size_t)e * NB;
    int run = base;
#pragma unroll 2
    for (int it = 0; it < 16; ++it) {
        int4 v = p[it * 64 + lane];
        int vv[4] = {v.x, v.y, v.z, v.w};
#pragma unroll
        for (int k = 0; k < 4; ++k) {
            unsigned long long m = __ballot(vv[k] == e);
            if (vv[k] == e)
                re[run + __popcll(m & below)] = w * 4096 + (it * 64 + lane) * 4 + k;
            run += __popcll(m);
        }
    }
    if (tid == 0) counts[e] = qc[0] + qc[1] + qc[2] + qc[3];
}

// ---------------- Kernel D: gather xn into bucket-sorted xns + rowof ------
__global__ __launch_bounds__(256) void gather_kernel(
    const unsigned short* __restrict__ xn, const int* __restrict__ counts,
    const int* __restrict__ rows, unsigned short* __restrict__ xns,
    int* __restrict__ rowof)
{
    int wave = threadIdx.x >> 6, lane = threadIdx.x & 63;
    int slot = blockIdx.x * 4 + wave;

    int pfx = 0, e = 0;
#pragma unroll
    for (int i = 0; i < NE; ++i) {
        int c = counts[i];
        if (e == i && slot >= pfx + c) { pfx += c; e = i + 1; }
    }
    int row = rows[(size_t)e * NB + (slot - pfx)];
    s8v v = *reinterpret_cast<const s8v*>(xn + (size_t)row * ND + lane * 8);
    *reinterpret_cast<s8v*>(xns + (size_t)slot * ND + lane * 8) = v;
    if (lane == 0) rowof[slot] = row;
}

// ---------------- Kernel E: 256x256 8-wave counted-vmcnt grouped GEMM -----
// 512 blocks x 512 thr (8 waves 2Mx4N, wave-tile 128x64, 0.375 ds_read/MFMA,
// 64 MFMA per barrier-pair -- the 256^2-template geometry). LDS 128KB dbuf
// (1 block/CU). Flat unit pool: u -> (e=u&15 [XCD-pinned], rt, ch); blocks
// grid-stride, skip empty -> balance-safe. Sync skeleton = R9's verified
// {barrier; issue(s+1); vmcnt(8); barrier; sched_barrier; compute(s)} with
// vmcnt(0) on the last step. T5 setprio around the MFMA cluster.
__global__ __launch_bounds__(512, 2) void mfma_mlp(
    const unsigned short* __restrict__ xns, const unsigned short* __restrict__ w1t,
    const float* __restrict__ b1, const float* __restrict__ w2,
    const int* __restrict__ counts, float* __restrict__ part)
{
    __shared__ unsigned short A_lds[2][BM * BK];   // 2 x 32 KiB
    __shared__ unsigned short B_lds[2][BN * BK];   // 2 x 32 KiB

    int bid = blockIdx.x;
    int tid = threadIdx.x, lane = tid & 63, wave = tid >> 6;   // wave 0..7
    int wm = wave & 1, wn = wave >> 1;                          // 2M x 4N

    int e = bid & 15;                    // constant per block (XCD pinning)
    int cnt = counts[e];
    int pfx = 0;
    for (int i = 0; i < e; ++i) pfx += counts[i];

    int rquad = lane >> 3;                          // 0..7
    int sbyte = ((lane & 7) * 16) ^ (rquad << 4);   // pre-swizzled src byte

    int g = lane >> 4;
    int fr = lane & 15;
    int sw = (lane & 7) << 4;
    int aoffs[8], boffs[4];                         // LDS read byte offsets
#pragma unroll
    for (int f = 0; f < 8; ++f) aoffs[f] = (wm * 128 + f * 16 + fr) * 128;
#pragma unroll
    for (int f = 0; f < 4; ++f) boffs[f] = (wn * 64 + f * 16 + fr) * 128;

    size_t ebase = (size_t)e * NH;                  // w1t row base (cols)

#define ISSUE_AB(buf, sbase, c0, ss)                                         \
    {   _Pragma("unroll")                                                    \
        for (int i = 0; i < 4; ++i) {                                        \
            int rloc = wave * 32 + i * 8 + rquad;                            \
            int slot = min((sbase) + rloc, NB - 1);                          \
            __builtin_amdgcn_global_load_lds(                                \
                (const __attribute__((address_space(1))) void*)              \
                    ((const char*)xns + (size_t)slot * 1024 + (ss) * 128 + sbyte), \
                (__attribute__((address_space(3))) void*)                    \
                    &A_lds[buf][(wave * 32 + i * 8) * BK], 16, 0, 0);        \
            __builtin_amdgcn_global_load_lds(                                \
                (const __attribute__((address_space(1))) void*)              \
                    ((const char*)w1t + (ebase + (c0) + rloc) * 1024 + (ss) * 128 + sbyte), \
                (__attribute__((address_space(3))) void*)                    \
                    &B_lds[buf][(wave * 32 + i * 8) * BK], 16, 0, 0); } }

    for (int u = bid; u < UCAP; u += GEMM_GRID) {
        int rest = u >> 4;
        int rt = rest >> 3;          // row tile (256 rows)
        int ch = rest & 7;           // 256-col chunk
        int rbase = rt * BM;
        if (rbase >= cnt) continue;  // block-uniform -> barrier-safe
        int sbase = pfx + rbase;
        int c0 = ch * BN;

        float b1v[4], w2v[4];
#pragma unroll
        for (int cf = 0; cf < 4; ++cf) {
            int col = c0 + wn * 64 + cf * 16 + fr;
            b1v[cf] = b1[ebase + col];
            w2v[cf] = w2[ebase + col];
        }

        f4v acc[8][4];
#pragma unroll
        for (int rf = 0; rf < 8; ++rf)
#pragma unroll
            for (int cf = 0; cf < 4; ++cf) acc[rf][cf] = (f4v){0.f, 0.f, 0.f, 0.f};

        // prologue: stage step 0 into buffers 0 (buf0 safe: last read 2 steps ago)
        ISSUE_AB(0, sbase, c0, 0);

#pragma unroll
        for (int ss = 0; ss < 8; ++ss) {
            int cb = ss & 1;
            __builtin_amdgcn_s_barrier();           // prior reads of cb^1 done
            if (ss < 7) {
                ISSUE_AB(cb ^ 1, sbase, c0, ss + 1);
                asm volatile("s_waitcnt vmcnt(8)" ::: "memory");  // step-ss landed
            } else {
                asm volatile("s_waitcnt vmcnt(0)" ::: "memory");
            }
            __builtin_amdgcn_s_barrier();           // buf cb ready for all waves
            __builtin_amdgcn_sched_barrier(0);

            __builtin_amdgcn_s_setprio(1);
#pragma unroll
            for (int ks = 0; ks < 2; ++ks) {
                int kb = (ks * 64 + g * 16) ^ sw;
                s8v a[8], bb[4];
#pragma unroll
                for (int rf = 0; rf < 8; ++rf)
                    a[rf] = *reinterpret_cast<const s8v*>(
                        (const char*)&A_lds[cb][0] + aoffs[rf] + kb);
#pragma unroll
                for (int cf = 0; cf < 4; ++cf)
                    bb[cf] = *reinterpret_cast<const s8v*>(
                        (const char*)&B_lds[cb][0] + boffs[cf] + kb);
#pragma unroll
                for (int rf = 0; rf < 8; ++rf)
#pragma unroll
                    for (int cf = 0; cf < 4; ++cf)
                        acc[rf][cf] = __builtin_amdgcn_mfma_f32_16x16x32_bf16(
                            a[rf], bb[cf], acc[rf][cf], 0, 0, 0);
            }
            __builtin_amdgcn_s_setprio(0);
        }

        // ---- epilogue: bias + gelu + w2 dot + 16-lane reduce + store -----
#pragma unroll
        for (int rf = 0; rf < 8; ++rf) {
            float pj[4] = {0.f, 0.f, 0.f, 0.f};
#pragma unroll
            for (int cf = 0; cf < 4; ++cf) {
#pragma unroll
                for (int j = 0; j < 4; ++j) {
                    float h = acc[rf][cf][j] + b1v[cf];
                    float uu = h * (0.7978845608f + 0.0356774081f * h * h);
                    float ex = __expf(2.f * uu);
                    float th = 1.f - 2.f / (ex + 1.f);
                    pj[j] = fmaf(0.5f * h * (1.f + th), w2v[cf], pj[j]);
                }
            }
#pragma unroll
            for (int m = 1; m < 16; m <<= 1)
#pragma unroll
                for (int j = 0; j < 4; ++j) pj[j] += __shfl_xor(pj[j], m);
            if ((lane & 15) == 0) {
#pragma unroll
                for (int j = 0; j < 4; ++j) {
                    int rloc = wm * 128 + rf * 16 + g * 4 + j;
                    if (rbase + rloc < cnt)
                        part[(size_t)(sbase + rloc) * NPW + ch * 4 + wn] = pj[j];
                }
            }
        }
    }
#undef ISSUE_AB
}

// ---------------- Kernel F: finalize logits (sum 32 partials + b2) --------
__global__ __launch_bounds__(256) void finalize_kernel(
    const float* __restrict__ part, const int* __restrict__ rowof,
    const int* __restrict__ idx_ws, const float* __restrict__ b2,
    float* __restrict__ logits)
{
    int s = blockIdx.x * 256 + threadIdx.x;
    const f4v* p = reinterpret_cast<const f4v*>(part + (size_t)s * NPW);
    float sum = 0.f;
#pragma unroll
    for (int i = 0; i < 8; ++i) {
        f4v v = p[i];
        sum += (v[0] + v[1]) + (v[2] + v[3]);
    }
    int row = rowof[s];
    logits[row] = sum + b2[idx_ws[row]];
}

extern "C" void kernel_launch(void* const* d_in, const int* in_sizes, int n_in,
                              void* d_out, int out_size, void* d_ws, size_t ws_size,
                              hipStream_t stream) {
    const float* z    = (const float*)d_in[0];
    const float* gw   = (const float*)d_in[1];
    const float* gb   = (const float*)d_in[2];
    const float* ln_s = (const float*)d_in[3];
    const float* ln_b = (const float*)d_in[4];
    const float* w1   = (const float*)d_in[5];
    const float* b1   = (const float*)d_in[6];
    const float* w2   = (const float*)d_in[7];
    const float* b2   = (const float*)d_in[8];

    float* logits = (float*)d_out;            // [NB]
    float* g_out  = (float*)d_out + NB;       // [NB, NE]

    char* ws = (char*)d_ws;
    unsigned short* w1t = (unsigned short*)(ws + WS_W1T_OFF);
    unsigned short* xn  = (unsigned short*)(ws + WS_XN_OFF);
    unsigned short* xns = (unsigned short*)(ws + WS_XNS_OFF);
    float* part  = (float*)(ws + WS_PART_OFF);
    int* idx_ws  = (int*)(ws + WS_IDX_OFF);
    int* rowof   = (int*)(ws + WS_ROWOF_OFF);
    int* cnts    = (int*)(ws + WS_CNT_OFF);
    int* rowl    = (int*)(ws + WS_ROWS_OFF);

    w1conv_kernel<<<NE * 64, 256, 0, stream>>>(w1, w1t);
    gate_ln_kernel<<<NB / 4, 256, 0, stream>>>(z, gw, gb, ln_s, ln_b,
                                               xn, idx_ws, g_out);
    bucket_kernel<<<NE, 256, 0, stream>>>(idx_ws, cnts, rowl);
    gather_kernel<<<NB / 4, 256, 0, stream>>>(xn, cnts, rowl, xns, rowof);
    mfma_mlp<<<GEMM_GRID, 512, 0, stream>>>(xns, w1t, b1, w2, cnts, part);
    finalize_kernel<<<NB / 256, 256, 0, stream>>>(part, rowof, idx_ws, b2,
                                                  logits);
}

// Round 14
// 155.545 us; speedup vs baseline: 1.0281x; 1.0281x over previous
//
#include <hip/hip_runtime.h>
#include <math.h>

#define NB 16384
#define ND 512
#define NE 16
#define NH 2048
#define BM 128            // rows per tile
#define BN 128            // cols per tile
#define BK 64             // k per step
#define NCH (NH / BN)     // 16 col chunks
#define NTB 8             // blocks per (e,ch) -> grid 2048
#define NPW (NCH * 2)     // partials per row (chunk x wn)
#define LN_EPS 1e-5f

typedef __attribute__((ext_vector_type(8))) short s8v;   // 8 bf16
typedef __attribute__((ext_vector_type(4))) float f4v;   // mfma acc

// ---- ws layout (bytes) ----
#define WS_W1T_OFF   ((size_t)0)
#define WS_W1T_BYTES ((size_t)NE * NH * ND * 2)           // 32 MiB
#define WS_XN_OFF    (WS_W1T_OFF + WS_W1T_BYTES)
#define WS_XN_BYTES  ((size_t)NB * ND * 2)                // 16 MiB
#define WS_XNS_OFF   (WS_XN_OFF + WS_XN_BYTES)
#define WS_XNS_BYTES ((size_t)NB * ND * 2)                // 16 MiB
#define WS_PART_OFF  (WS_XNS_OFF + WS_XNS_BYTES)
#define WS_PART_BYTES ((size_t)NB * NPW * 4)              // 2 MiB
#define WS_IDX_OFF   (WS_PART_OFF + WS_PART_BYTES)
#define WS_ROWOF_OFF (WS_IDX_OFF + (size_t)NB * 4)
#define WS_CNT_OFF   (WS_ROWOF_OFF + (size_t)NB * 4)
#define WS_ROWS_OFF  (WS_CNT_OFF + 256)

__device__ __forceinline__ unsigned short bf16_rne(float f) {
    unsigned u = __float_as_uint(f);
    unsigned r = (u + 0x7fffu + ((u >> 16) & 1u)) >> 16;
    return (unsigned short)r;
}

// ---------------- Kernel A: w1 [E][D][H] f32 -> w1t [E][H][D] bf16 --------
__global__ __launch_bounds__(256) void w1conv_kernel(
    const float* __restrict__ w1, unsigned short* __restrict__ w1t)
{
    int bid = blockIdx.x;
    int e = bid & 15;
    int rest = bid >> 4;
    int db = rest & 7;
    int hb = rest >> 3;
    int h = hb * 256 + threadIdx.x;

    const float* src = w1 + ((size_t)e * ND + db * 64) * NH + h;
    unsigned int u[32];
#pragma unroll
    for (int p = 0; p < 32; ++p) {
        float f0 = src[(size_t)(2 * p) * NH];
        float f1 = src[(size_t)(2 * p + 1) * NH];
        u[p] = (unsigned)bf16_rne(f0) | ((unsigned)bf16_rne(f1) << 16);
    }
    uint4* dst = reinterpret_cast<uint4*>(
        w1t + ((size_t)e * NH + h) * ND + db * 64);
#pragma unroll
    for (int p = 0; p < 8; ++p)
        dst[p] = make_uint4(u[4 * p], u[4 * p + 1], u[4 * p + 2], u[4 * p + 3]);
}

// ---------------- Kernel B: gate + softmax + argmax + LN + xn(bf16) -------
__global__ __launch_bounds__(256) void gate_ln_kernel(
    const float* __restrict__ z, const float* __restrict__ gw,
    const float* __restrict__ gb, const float* __restrict__ ln_s,
    const float* __restrict__ ln_b, unsigned short* __restrict__ xn,
    int* __restrict__ idx_ws, float* __restrict__ g_out)
{
    int wave = threadIdx.x >> 6;
    int lane = threadIdx.x & 63;
    int b = blockIdx.x * 4 + wave;
    int q = lane & 3, dg = lane >> 2;

    const float* zr = z + (size_t)b * ND;
    float4 zv[8];
#pragma unroll
    for (int i = 0; i < 8; ++i)
        zv[i] = *reinterpret_cast<const float4*>(zr + dg * 32 + i * 4);

    float sum = 0.f, ssq = 0.f;
    float ga[4] = {0.f, 0.f, 0.f, 0.f};
#pragma unroll
    for (int i = 0; i < 8; ++i) {
        float zs[4] = {zv[i].x, zv[i].y, zv[i].z, zv[i].w};
#pragma unroll
        for (int t = 0; t < 4; ++t) {
            int d = dg * 32 + i * 4 + t;
            float4 w4 = *reinterpret_cast<const float4*>(gw + (size_t)d * NE + q * 4);
            ga[0] = fmaf(zs[t], w4.x, ga[0]);
            ga[1] = fmaf(zs[t], w4.y, ga[1]);
            ga[2] = fmaf(zs[t], w4.z, ga[2]);
            ga[3] = fmaf(zs[t], w4.w, ga[3]);
            sum += zs[t];
            ssq = fmaf(zs[t], zs[t], ssq);
        }
    }
#pragma unroll
    for (int m = 4; m <= 32; m <<= 1) {
        sum += __shfl_xor(sum, m);
        ssq += __shfl_xor(ssq, m);
#pragma unroll
        for (int j = 0; j < 4; ++j) ga[j] += __shfl_xor(ga[j], m);
    }
#pragma unroll
    for (int j = 0; j < 4; ++j) ga[j] += gb[q * 4 + j];

    float mu = sum * (1.f / ND);
    float var = ssq * (1.f / ND) - mu * mu;
    float rstd = rsqrtf(var + LN_EPS);

    float lmax = fmaxf(fmaxf(ga[0], ga[1]), fmaxf(ga[2], ga[3]));
    lmax = fmaxf(lmax, __shfl_xor(lmax, 1));
    lmax = fmaxf(lmax, __shfl_xor(lmax, 2));
    float ge[4], lsum = 0.f;
#pragma unroll
    for (int j = 0; j < 4; ++j) { ge[j] = __expf(ga[j] - lmax); lsum += ge[j]; }
    lsum += __shfl_xor(lsum, 1);
    lsum += __shfl_xor(lsum, 2);
    float rden = 1.f / lsum;

    int li = 1000;
#pragma unroll
    for (int j = 3; j >= 0; --j) if (ga[j] == lmax) li = q * 4 + j;
    li = min(li, __shfl_xor(li, 1));
    li = min(li, __shfl_xor(li, 2));

    // g write: lane l<16 wants expert l = (l>>2)*4 + (l&3)
    float gv0 = ge[0] * rden, gv1 = ge[1] * rden;
    float gv2 = ge[2] * rden, gv3 = ge[3] * rden;
    int srcl = lane >> 2;
    float t0 = __shfl(gv0, srcl), t1 = __shfl(gv1, srcl);
    float t2 = __shfl(gv2, srcl), t3 = __shfl(gv3, srcl);
    float gval = (q == 0) ? t0 : (q == 1) ? t1 : (q == 2) ? t2 : t3;
    if (lane < NE) g_out[(size_t)b * NE + lane] = gval;

    // xn: lane writes d = dg*32 + q*8 .. +8 (16B)
    float4 xa, xc;
    if (q == 0)      { xa = zv[0]; xc = zv[1]; }
    else if (q == 1) { xa = zv[2]; xc = zv[3]; }
    else if (q == 2) { xa = zv[4]; xc = zv[5]; }
    else             { xa = zv[6]; xc = zv[7]; }
    int dofs = dg * 32 + q * 8;
    const float* ls = ln_s + (size_t)li * ND + dofs;
    const float* lb = ln_b + (size_t)li * ND + dofs;
    float4 s0 = *reinterpret_cast<const float4*>(ls);
    float4 s1 = *reinterpret_cast<const float4*>(ls + 4);
    float4 u0 = *reinterpret_cast<const float4*>(lb);
    float4 u1 = *reinterpret_cast<const float4*>(lb + 4);
    unsigned short xb[8];
    xb[0] = bf16_rne((xa.x - mu) * rstd * s0.x + u0.x);
    xb[1] = bf16_rne((xa.y - mu) * rstd * s0.y + u0.y);
    xb[2] = bf16_rne((xa.z - mu) * rstd * s0.z + u0.z);
    xb[3] = bf16_rne((xa.w - mu) * rstd * s0.w + u0.w);
    xb[4] = bf16_rne((xc.x - mu) * rstd * s1.x + u1.x);
    xb[5] = bf16_rne((xc.y - mu) * rstd * s1.y + u1.y);
    xb[6] = bf16_rne((xc.z - mu) * rstd * s1.z + u1.z);
    xb[7] = bf16_rne((xc.w - mu) * rstd * s1.w + u1.w);
    *reinterpret_cast<s8v*>(xn + (size_t)b * ND + dofs) =
        *reinterpret_cast<s8v*>(xb);

    if (lane == 0) idx_ws[b] = li;
}

// ---------------- Kernel C: bucket build, 4-wave two-pass -----------------
__global__ __launch_bounds__(256) void bucket_kernel(
    const int* __restrict__ idx_ws, int* __restrict__ counts,
    int* __restrict__ rows)
{
    __shared__ int qc[4];
    int e = blockIdx.x;
    int tid = threadIdx.x, w = tid >> 6, lane = tid & 63;
    const int4* p = reinterpret_cast<const int4*>(idx_ws) + (size_t)w * 1024;

    int c = 0;
#pragma unroll 4
    for (int it = 0; it < 16; ++it) {
        int4 v = p[it * 64 + lane];
        c += (v.x == e) + (v.y == e) + (v.z == e) + (v.w == e);
    }
#pragma unroll
    for (int m = 1; m < 64; m <<= 1) c += __shfl_xor(c, m);
    if (lane == 0) qc[w] = c;
    __syncthreads();

    int base = 0;
    for (int j = 0; j < w; ++j) base += qc[j];
    unsigned long long below = (lane == 0) ? 0ull : ((~0ull) >> (64 - lane));
    int* re = rows + (size_t)e * NB;
    int run = base;
#pragma unroll 2
    for (int it = 0; it < 16; ++it) {
        int4 v = p[it * 64 + lane];
        int vv[4] = {v.x, v.y, v.z, v.w};
#pragma unroll
        for (int k = 0; k < 4; ++k) {
            unsigned long long m = __ballot(vv[k] == e);
            if (vv[k] == e)
                re[run + __popcll(m & below)] = w * 4096 + (it * 64 + lane) * 4 + k;
            run += __popcll(m);
        }
    }
    if (tid == 0) counts[e] = qc[0] + qc[1] + qc[2] + qc[3];
}

// ---------------- Kernel D: gather xn into bucket-sorted xns + rowof ------
__global__ __launch_bounds__(256) void gather_kernel(
    const unsigned short* __restrict__ xn, const int* __restrict__ counts,
    const int* __restrict__ rows, unsigned short* __restrict__ xns,
    int* __restrict__ rowof)
{
    int wave = threadIdx.x >> 6, lane = threadIdx.x & 63;
    int slot = blockIdx.x * 4 + wave;

    int pfx = 0, e = 0;
#pragma unroll
    for (int i = 0; i < NE; ++i) {
        int c = counts[i];
        if (e == i && slot >= pfx + c) { pfx += c; e = i + 1; }
    }
    int row = rows[(size_t)e * NB + (slot - pfx)];
    s8v v = *reinterpret_cast<const s8v*>(xn + (size_t)row * ND + lane * 8);
    *reinterpret_cast<s8v*>(xns + (size_t)slot * ND + lane * 8) = v;
    if (lane == 0) rowof[slot] = row;
}

// ---------------- Kernel E: m97-recipe grouped MFMA GEMM, reg-diet --------
// R12 structure (proven: single-buf 32KB LDS, 2 barriers/K-step, gload_lds
// w=16, src-side XOR pre-swizzle) with the occupancy fix: acc = 64 AGPR
// counts against the unified file, so arch-VGPR is dieted to ~75 via
// 32-bit voffsets off uniform bases (computed once per tile/block; per-step
// +ss*128 folds into the instruction offset field). __launch_bounds__(256,3)
// -> 3 waves/SIMD (R12's true occupancy was 2: 108 VGPR + 64 AGPR = 172).
__global__ __launch_bounds__(256, 3) void mfma_mlp(
    const unsigned short* __restrict__ xns, const unsigned short* __restrict__ w1t,
    const float* __restrict__ b1, const float* __restrict__ w2,
    const int* __restrict__ counts, float* __restrict__ part)
{
    __shared__ unsigned short A_lds[BM * BK];   // 16 KiB
    __shared__ unsigned short B_lds[BN * BK];   // 16 KiB

    int bid = blockIdx.x;
    int e = bid & 15;
    int rest = bid >> 4;
    int ch = rest & 15;
    int tb0 = rest >> 4;        // 0..7
    int c0 = ch * BN;
    int tid = threadIdx.x, lane = tid & 63, wave = tid >> 6;
    int wm = wave & 1, wn = wave >> 1;

    int cnt = counts[e];
    int pfx = 0;
    for (int i = 0; i < e; ++i) pfx += counts[i];

    int rquad = lane >> 3;                          // 0..7
    int sbyte = ((lane & 7) * 16) ^ (rquad << 4);   // pre-swizzled src byte

    const char* xb = (const char*)xns;              // uniform bases
    const char* wb = (const char*)w1t;

    // B 32-bit voffsets (constant per block)
    unsigned boff32[4];
#pragma unroll
    for (int i = 0; i < 4; ++i) {
        int cl = (wave * 4 + i) * 8 + rquad;
        boff32[i] = (unsigned)((e * NH + c0 + cl) * 1024) + sbyte;
    }

    int g = lane >> 4;
    int fr = lane & 15;
    int sw = (lane & 7) << 4;
    int kb0 = (g * 16) ^ sw, kb1 = (64 + g * 16) ^ sw;
    int aoffs[4], boffs[4];                         // LDS read byte offsets
#pragma unroll
    for (int f = 0; f < 4; ++f) {
        aoffs[f] = (wm * 64 + f * 16 + fr) * 128;
        boffs[f] = (wn * 64 + f * 16 + fr) * 128;
    }

    for (int tb = tb0; tb * BM < cnt; tb += NTB) {
        int rbase = tb * BM;
        int sbase = pfx + rbase;

        // A 32-bit voffsets for this tile
        unsigned aoff32[4];
#pragma unroll
        for (int i = 0; i < 4; ++i) {
            int rloc = (wave * 4 + i) * 8 + rquad;
            int slot = min(sbase + rloc, NB - 1);
            aoff32[i] = (unsigned)(slot * 1024) + sbyte;
        }

        f4v acc[4][4];
#pragma unroll
        for (int rf = 0; rf < 4; ++rf)
#pragma unroll
            for (int cf = 0; cf < 4; ++cf) acc[rf][cf] = (f4v){0.f, 0.f, 0.f, 0.f};

#pragma unroll
        for (int ss = 0; ss < 8; ++ss) {
            __syncthreads();    // prior step's reads done before overwrite
#pragma unroll
            for (int i = 0; i < 4; ++i) {
                __builtin_amdgcn_global_load_lds(
                    (const __attribute__((address_space(1))) void*)
                        (xb + aoff32[i] + ss * 128),
                    (__attribute__((address_space(3))) void*)
                        &A_lds[(wave * 4 + i) * 8 * BK], 16, 0, 0);
                __builtin_amdgcn_global_load_lds(
                    (const __attribute__((address_space(1))) void*)
                        (wb + boff32[i] + ss * 128),
                    (__attribute__((address_space(3))) void*)
                        &B_lds[(wave * 4 + i) * 8 * BK], 16, 0, 0);
            }
            __syncthreads();    // vmcnt(0) drain; other blocks cover stall

            // ---- compute step ss ----
#pragma unroll
            for (int ks = 0; ks < 2; ++ks) {
                int kb = ks ? kb1 : kb0;
                s8v a[4], bb[4];
#pragma unroll
                for (int rf = 0; rf < 4; ++rf)
                    a[rf] = *reinterpret_cast<const s8v*>(
                        (const char*)A_lds + aoffs[rf] + kb);
#pragma unroll
                for (int cf = 0; cf < 4; ++cf)
                    bb[cf] = *reinterpret_cast<const s8v*>(
                        (const char*)B_lds + boffs[cf] + kb);
#pragma unroll
                for (int rf = 0; rf < 4; ++rf)
#pragma unroll
                    for (int cf = 0; cf < 4; ++cf)
                        acc[rf][cf] = __builtin_amdgcn_mfma_f32_16x16x32_bf16(
                            a[rf], bb[cf], acc[rf][cf], 0, 0, 0);
            }
        }

        // ---- epilogue: bias + gelu + w2 dot + 16-lane reduce + store -----
        // (b1v/w2v loaded here, after the MFMA loop, to keep loop pressure low)
        float b1v[4], w2v[4];
#pragma unroll
        for (int cf = 0; cf < 4; ++cf) {
            int col = c0 + wn * 64 + cf * 16 + fr;
            b1v[cf] = b1[(size_t)e * NH + col];
            w2v[cf] = w2[(size_t)e * NH + col];
        }
#pragma unroll
        for (int rf = 0; rf < 4; ++rf) {
            float pj[4] = {0.f, 0.f, 0.f, 0.f};
#pragma unroll
            for (int cf = 0; cf < 4; ++cf) {
#pragma unroll
                for (int j = 0; j < 4; ++j) {
                    float h = acc[rf][cf][j] + b1v[cf];
                    float uu = h * (0.7978845608f + 0.0356774081f * h * h);
                    float ex = __expf(2.f * uu);
                    float th = 1.f - 2.f / (ex + 1.f);
                    pj[j] = fmaf(0.5f * h * (1.f + th), w2v[cf], pj[j]);
                }
            }
#pragma unroll
            for (int m = 1; m < 16; m <<= 1)
#pragma unroll
                for (int j = 0; j < 4; ++j) pj[j] += __shfl_xor(pj[j], m);
            if ((lane & 15) == 0) {
#pragma unroll
                for (int j = 0; j < 4; ++j) {
                    int rloc = wm * 64 + rf * 16 + g * 4 + j;
                    if (rbase + rloc < cnt)
                        part[(size_t)(sbase + rloc) * NPW + ch * 2 + wn] = pj[j];
                }
            }
        }
    }
}

// ---------------- Kernel F: finalize logits (sum 32 partials + b2) --------
__global__ __launch_bounds__(256) void finalize_kernel(
    const float* __restrict__ part, const int* __restrict__ rowof,
    const int* __restrict__ idx_ws, const float* __restrict__ b2,
    float* __restrict__ logits)
{
    int s = blockIdx.x * 256 + threadIdx.x;
    const f4v* p = reinterpret_cast<const f4v*>(part + (size_t)s * NPW);
    float sum = 0.f;
#pragma unroll
    for (int i = 0; i < 8; ++i) {
        f4v v = p[i];
        sum += (v[0] + v[1]) + (v[2] + v[3]);
    }
    int row = rowof[s];
    logits[row] = sum + b2[idx_ws[row]];
}

extern "C" void kernel_launch(void* const* d_in, const int* in_sizes, int n_in,
                              void* d_out, int out_size, void* d_ws, size_t ws_size,
                              hipStream_t stream) {
    const float* z    = (const float*)d_in[0];
    const float* gw   = (const float*)d_in[1];
    const float* gb   = (const float*)d_in[2];
    const float* ln_s = (const float*)d_in[3];
    const float* ln_b = (const float*)d_in[4];
    const float* w1   = (const float*)d_in[5];
    const float* b1   = (const float*)d_in[6];
    const float* w2   = (const float*)d_in[7];
    const float* b2   = (const float*)d_in[8];

    float* logits = (float*)d_out;            // [NB]
    float* g_out  = (float*)d_out + NB;       // [NB, NE]

    char* ws = (char*)d_ws;
    unsigned short* w1t = (unsigned short*)(ws + WS_W1T_OFF);
    unsigned short* xn  = (unsigned short*)(ws + WS_XN_OFF);
    unsigned short* xns = (unsigned short*)(ws + WS_XNS_OFF);
    float* part  = (float*)(ws + WS_PART_OFF);
    int* idx_ws  = (int*)(ws + WS_IDX_OFF);
    int* rowof   = (int*)(ws + WS_ROWOF_OFF);
    int* cnts    = (int*)(ws + WS_CNT_OFF);
    int* rowl    = (int*)(ws + WS_ROWS_OFF);

    w1conv_kernel<<<NE * 64, 256, 0, stream>>>(w1, w1t);
    gate_ln_kernel<<<NB / 4, 256, 0, stream>>>(z, gw, gb, ln_s, ln_b,
                                               xn, idx_ws, g_out);
    bucket_kernel<<<NE, 256, 0, stream>>>(idx_ws, cnts, rowl);
    gather_kernel<<<NB / 4, 256, 0, stream>>>(xn, cnts, rowl, xns, rowof);
    mfma_mlp<<<NE * NCH * NTB, 256, 0, stream>>>(xns, w1t, b1, w2, cnts, part);
    finalize_kernel<<<NB / 256, 256, 0, stream>>>(part, rowof, idx_ws, b2,
                                                  logits);
}

// Round 15
// 142.457 us; speedup vs baseline: 1.1225x; 1.0919x over previous
//
#include <hip/hip_runtime.h>
#include <math.h>

#define NB 16384
#define ND 512
#define NE 16
#define NH 2048
#define BM 128            // rows per tile
#define BN 128            // cols per tile
#define BK 64             // k per step
#define NCH (NH / BN)     // 16 col chunks
#define NPW (NCH * 2)     // partials per row (chunk x wn)
#define LN_EPS 1e-5f

typedef __attribute__((ext_vector_type(8))) short s8v;   // 8 bf16
typedef __attribute__((ext_vector_type(4))) float f4v;   // mfma acc

// ---- ws layout (bytes) ----
#define WS_W1T_OFF   ((size_t)0)
#define WS_W1T_BYTES ((size_t)NE * NH * ND * 2)           // 32 MiB
#define WS_XN_OFF    (WS_W1T_OFF + WS_W1T_BYTES)
#define WS_XN_BYTES  ((size_t)NB * ND * 2)                // 16 MiB
#define WS_XNS_OFF   (WS_XN_OFF + WS_XN_BYTES)
#define WS_XNS_BYTES ((size_t)NB * ND * 2)                // 16 MiB
#define WS_PART_OFF  (WS_XNS_OFF + WS_XNS_BYTES)
#define WS_PART_BYTES ((size_t)NB * NPW * 4)              // 2 MiB
#define WS_IDX_OFF   (WS_PART_OFF + WS_PART_BYTES)
#define WS_ROWOF_OFF (WS_IDX_OFF + (size_t)NB * 4)
#define WS_CNT_OFF   (WS_ROWOF_OFF + (size_t)NB * 4)
#define WS_ROWS_OFF  (WS_CNT_OFF + 256)

__device__ __forceinline__ unsigned short bf16_rne(float f) {
    unsigned u = __float_as_uint(f);
    unsigned r = (u + 0x7fffu + ((u >> 16) & 1u)) >> 16;
    return (unsigned short)r;
}

// ---------------- Kernel B+A fused: gate/LN/xn  OR  w1conv ----------------
// grid = NB/4 + NE*64. Blocks < NB/4 do gate work; the rest convert w1.
// Both are memory-bound and independent -> they overlap in one launch.
__global__ __launch_bounds__(256) void gate_w1_kernel(
    const float* __restrict__ z, const float* __restrict__ gw,
    const float* __restrict__ gb, const float* __restrict__ ln_s,
    const float* __restrict__ ln_b, const float* __restrict__ w1,
    unsigned short* __restrict__ w1t, unsigned short* __restrict__ xn,
    int* __restrict__ idx_ws, float* __restrict__ g_out)
{
    if (blockIdx.x >= NB / 4) {
        // ---- w1conv part: w1 [E][D][H] f32 -> w1t [E][H][D] bf16 ----
        int bid = blockIdx.x - NB / 4;
        int e = bid & 15;
        int rest = bid >> 4;
        int db = rest & 7;
        int hb = rest >> 3;
        int h = hb * 256 + threadIdx.x;

        const float* src = w1 + ((size_t)e * ND + db * 64) * NH + h;
        unsigned int u[32];
#pragma unroll
        for (int p = 0; p < 32; ++p) {
            float f0 = src[(size_t)(2 * p) * NH];
            float f1 = src[(size_t)(2 * p + 1) * NH];
            u[p] = (unsigned)bf16_rne(f0) | ((unsigned)bf16_rne(f1) << 16);
        }
        uint4* dst = reinterpret_cast<uint4*>(
            w1t + ((size_t)e * NH + h) * ND + db * 64);
#pragma unroll
        for (int p = 0; p < 8; ++p)
            dst[p] = make_uint4(u[4 * p], u[4 * p + 1], u[4 * p + 2], u[4 * p + 3]);
        return;
    }

    int wave = threadIdx.x >> 6;
    int lane = threadIdx.x & 63;
    int b = blockIdx.x * 4 + wave;
    int q = lane & 3, dg = lane >> 2;

    const float* zr = z + (size_t)b * ND;
    float4 zv[8];
#pragma unroll
    for (int i = 0; i < 8; ++i)
        zv[i] = *reinterpret_cast<const float4*>(zr + dg * 32 + i * 4);

    float sum = 0.f, ssq = 0.f;
    float ga[4] = {0.f, 0.f, 0.f, 0.f};
#pragma unroll
    for (int i = 0; i < 8; ++i) {
        float zs[4] = {zv[i].x, zv[i].y, zv[i].z, zv[i].w};
#pragma unroll
        for (int t = 0; t < 4; ++t) {
            int d = dg * 32 + i * 4 + t;
            float4 w4 = *reinterpret_cast<const float4*>(gw + (size_t)d * NE + q * 4);
            ga[0] = fmaf(zs[t], w4.x, ga[0]);
            ga[1] = fmaf(zs[t], w4.y, ga[1]);
            ga[2] = fmaf(zs[t], w4.z, ga[2]);
            ga[3] = fmaf(zs[t], w4.w, ga[3]);
            sum += zs[t];
            ssq = fmaf(zs[t], zs[t], ssq);
        }
    }
#pragma unroll
    for (int m = 4; m <= 32; m <<= 1) {
        sum += __shfl_xor(sum, m);
        ssq += __shfl_xor(ssq, m);
#pragma unroll
        for (int j = 0; j < 4; ++j) ga[j] += __shfl_xor(ga[j], m);
    }
#pragma unroll
    for (int j = 0; j < 4; ++j) ga[j] += gb[q * 4 + j];

    float mu = sum * (1.f / ND);
    float var = ssq * (1.f / ND) - mu * mu;
    float rstd = rsqrtf(var + LN_EPS);

    float lmax = fmaxf(fmaxf(ga[0], ga[1]), fmaxf(ga[2], ga[3]));
    lmax = fmaxf(lmax, __shfl_xor(lmax, 1));
    lmax = fmaxf(lmax, __shfl_xor(lmax, 2));
    float ge[4], lsum = 0.f;
#pragma unroll
    for (int j = 0; j < 4; ++j) { ge[j] = __expf(ga[j] - lmax); lsum += ge[j]; }
    lsum += __shfl_xor(lsum, 1);
    lsum += __shfl_xor(lsum, 2);
    float rden = 1.f / lsum;

    int li = 1000;
#pragma unroll
    for (int j = 3; j >= 0; --j) if (ga[j] == lmax) li = q * 4 + j;
    li = min(li, __shfl_xor(li, 1));
    li = min(li, __shfl_xor(li, 2));

    // g write: lane l<16 wants expert l = (l>>2)*4 + (l&3)
    float gv0 = ge[0] * rden, gv1 = ge[1] * rden;
    float gv2 = ge[2] * rden, gv3 = ge[3] * rden;
    int srcl = lane >> 2;
    float t0 = __shfl(gv0, srcl), t1 = __shfl(gv1, srcl);
    float t2 = __shfl(gv2, srcl), t3 = __shfl(gv3, srcl);
    float gval = (q == 0) ? t0 : (q == 1) ? t1 : (q == 2) ? t2 : t3;
    if (lane < NE) g_out[(size_t)b * NE + lane] = gval;

    // xn: lane writes d = dg*32 + q*8 .. +8 (16B)
    float4 xa, xc;
    if (q == 0)      { xa = zv[0]; xc = zv[1]; }
    else if (q == 1) { xa = zv[2]; xc = zv[3]; }
    else if (q == 2) { xa = zv[4]; xc = zv[5]; }
    else             { xa = zv[6]; xc = zv[7]; }
    int dofs = dg * 32 + q * 8;
    const float* ls = ln_s + (size_t)li * ND + dofs;
    const float* lb = ln_b + (size_t)li * ND + dofs;
    float4 s0 = *reinterpret_cast<const float4*>(ls);
    float4 s1 = *reinterpret_cast<const float4*>(ls + 4);
    float4 u0 = *reinterpret_cast<const float4*>(lb);
    float4 u1 = *reinterpret_cast<const float4*>(lb + 4);
    unsigned short xb[8];
    xb[0] = bf16_rne((xa.x - mu) * rstd * s0.x + u0.x);
    xb[1] = bf16_rne((xa.y - mu) * rstd * s0.y + u0.y);
    xb[2] = bf16_rne((xa.z - mu) * rstd * s0.z + u0.z);
    xb[3] = bf16_rne((xa.w - mu) * rstd * s0.w + u0.w);
    xb[4] = bf16_rne((xc.x - mu) * rstd * s1.x + u1.x);
    xb[5] = bf16_rne((xc.y - mu) * rstd * s1.y + u1.y);
    xb[6] = bf16_rne((xc.z - mu) * rstd * s1.z + u1.z);
    xb[7] = bf16_rne((xc.w - mu) * rstd * s1.w + u1.w);
    *reinterpret_cast<s8v*>(xn + (size_t)b * ND + dofs) =
        *reinterpret_cast<s8v*>(xb);

    if (lane == 0) idx_ws[b] = li;
}

// ---------------- Kernel C: bucket build, 4-wave two-pass -----------------
__global__ __launch_bounds__(256) void bucket_kernel(
    const int* __restrict__ idx_ws, int* __restrict__ counts,
    int* __restrict__ rows)
{
    __shared__ int qc[4];
    int e = blockIdx.x;
    int tid = threadIdx.x, w = tid >> 6, lane = tid & 63;
    const int4* p = reinterpret_cast<const int4*>(idx_ws) + (size_t)w * 1024;

    int c = 0;
#pragma unroll 4
    for (int it = 0; it < 16; ++it) {
        int4 v = p[it * 64 + lane];
        c += (v.x == e) + (v.y == e) + (v.z == e) + (v.w == e);
    }
#pragma unroll
    for (int m = 1; m < 64; m <<= 1) c += __shfl_xor(c, m);
    if (lane == 0) qc[w] = c;
    __syncthreads();

    int base = 0;
    for (int j = 0; j < w; ++j) base += qc[j];
    unsigned long long below = (lane == 0) ? 0ull : ((~0ull) >> (64 - lane));
    int* re = rows + (size_t)e * NB;
    int run = base;
#pragma unroll 2
    for (int it = 0; it < 16; ++it) {
        int4 v = p[it * 64 + lane];
        int vv[4] = {v.x, v.y, v.z, v.w};
#pragma unroll
        for (int k = 0; k < 4; ++k) {
            unsigned long long m = __ballot(vv[k] == e);
            if (vv[k] == e)
                re[run + __popcll(m & below)] = w * 4096 + (it * 64 + lane) * 4 + k;
            run += __popcll(m);
        }
    }
    if (tid == 0) counts[e] = qc[0] + qc[1] + qc[2] + qc[3];
}

// ---------------- Kernel D: gather xn into bucket-sorted xns + rowof ------
__global__ __launch_bounds__(256) void gather_kernel(
    const unsigned short* __restrict__ xn, const int* __restrict__ counts,
    const int* __restrict__ rows, unsigned short* __restrict__ xns,
    int* __restrict__ rowof)
{
    int wave = threadIdx.x >> 6, lane = threadIdx.x & 63;
    int slot = blockIdx.x * 4 + wave;

    int pfx = 0, e = 0;
#pragma unroll
    for (int i = 0; i < NE; ++i) {
        int c = counts[i];
        if (e == i && slot >= pfx + c) { pfx += c; e = i + 1; }
    }
    int row = rows[(size_t)e * NB + (slot - pfx)];
    s8v v = *reinterpret_cast<const s8v*>(xn + (size_t)row * ND + lane * 8);
    *reinterpret_cast<s8v*>(xns + (size_t)slot * ND + lane * 8) = v;
    if (lane == 0) rowof[slot] = row;
}

// ---------------- Kernel E: m97-recipe grouped GEMM, L2-phased ------------
// R14 structure (single-buf 32KB LDS, 2 barriers/K-step, gload_lds w=16,
// src-side XOR pre-swizzle, 32-bit voffsets, (256,3)) + TEMPORAL EXPERT
// PHASING: grid 2048, phase=bid>>10, e=(bid&7)+8*phase. Within a residency
// round each XCD (bid%8) serves ONE expert -> working set w1t 2MB + xns
// 1MB = 3MB < 4MiB L2 -> per-step vmcnt drain waits on L2 (~200cy) not
// HBM-queue (~10k cy). Epilogue gelu = clamped Pade-5/4 tanh (1 rcp, 0 exp).
__global__ __launch_bounds__(256, 3) void mfma_mlp(
    const unsigned short* __restrict__ xns, const unsigned short* __restrict__ w1t,
    const float* __restrict__ b1, const float* __restrict__ w2,
    const int* __restrict__ counts, float* __restrict__ part)
{
    __shared__ unsigned short A_lds[BM * BK];   // 16 KiB
    __shared__ unsigned short B_lds[BN * BK];   // 16 KiB

    int bid = blockIdx.x;
    int phase = bid >> 10;                      // 0..1
    int e = (bid & 7) + phase * 8;              // XCD bid%8 -> one expert/phase
    int rest = (bid >> 3) & 127;
    int ch = rest & 15;
    int tb0 = rest >> 4;                        // 0..7
    int c0 = ch * BN;
    int tid = threadIdx.x, lane = tid & 63, wave = tid >> 6;
    int wm = wave & 1, wn = wave >> 1;

    int cnt = counts[e];
    int pfx = 0;
    for (int i = 0; i < e; ++i) pfx += counts[i];

    int rquad = lane >> 3;                          // 0..7
    int sbyte = ((lane & 7) * 16) ^ (rquad << 4);   // pre-swizzled src byte

    const char* xb = (const char*)xns;              // uniform bases
    const char* wb = (const char*)w1t;

    // B 32-bit voffsets (constant per block)
    unsigned boff32[4];
#pragma unroll
    for (int i = 0; i < 4; ++i) {
        int cl = (wave * 4 + i) * 8 + rquad;
        boff32[i] = (unsigned)((e * NH + c0 + cl) * 1024) + sbyte;
    }

    int g = lane >> 4;
    int fr = lane & 15;
    int sw = (lane & 7) << 4;
    int kb0 = (g * 16) ^ sw, kb1 = (64 + g * 16) ^ sw;
    int aoffs[4], boffs[4];                         // LDS read byte offsets
#pragma unroll
    for (int f = 0; f < 4; ++f) {
        aoffs[f] = (wm * 64 + f * 16 + fr) * 128;
        boffs[f] = (wn * 64 + f * 16 + fr) * 128;
    }

    for (int tb = tb0; tb * BM < cnt; tb += 8) {
        int rbase = tb * BM;
        int sbase = pfx + rbase;

        // A 32-bit voffsets for this tile
        unsigned aoff32[4];
#pragma unroll
        for (int i = 0; i < 4; ++i) {
            int rloc = (wave * 4 + i) * 8 + rquad;
            int slot = min(sbase + rloc, NB - 1);
            aoff32[i] = (unsigned)(slot * 1024) + sbyte;
        }

        f4v acc[4][4];
#pragma unroll
        for (int rf = 0; rf < 4; ++rf)
#pragma unroll
            for (int cf = 0; cf < 4; ++cf) acc[rf][cf] = (f4v){0.f, 0.f, 0.f, 0.f};

#pragma unroll
        for (int ss = 0; ss < 8; ++ss) {
            __syncthreads();    // prior step's reads done before overwrite
#pragma unroll
            for (int i = 0; i < 4; ++i) {
                __builtin_amdgcn_global_load_lds(
                    (const __attribute__((address_space(1))) void*)
                        (xb + aoff32[i] + ss * 128),
                    (__attribute__((address_space(3))) void*)
                        &A_lds[(wave * 4 + i) * 8 * BK], 16, 0, 0);
                __builtin_amdgcn_global_load_lds(
                    (const __attribute__((address_space(1))) void*)
                        (wb + boff32[i] + ss * 128),
                    (__attribute__((address_space(3))) void*)
                        &B_lds[(wave * 4 + i) * 8 * BK], 16, 0, 0);
            }
            __syncthreads();    // vmcnt(0) drain; L2-resident -> short

            // ---- compute step ss ----
#pragma unroll
            for (int ks = 0; ks < 2; ++ks) {
                int kb = ks ? kb1 : kb0;
                s8v a[4], bb[4];
#pragma unroll
                for (int rf = 0; rf < 4; ++rf)
                    a[rf] = *reinterpret_cast<const s8v*>(
                        (const char*)A_lds + aoffs[rf] + kb);
#pragma unroll
                for (int cf = 0; cf < 4; ++cf)
                    bb[cf] = *reinterpret_cast<const s8v*>(
                        (const char*)B_lds + boffs[cf] + kb);
#pragma unroll
                for (int rf = 0; rf < 4; ++rf)
#pragma unroll
                    for (int cf = 0; cf < 4; ++cf)
                        acc[rf][cf] = __builtin_amdgcn_mfma_f32_16x16x32_bf16(
                            a[rf], bb[cf], acc[rf][cf], 0, 0, 0);
            }
        }

        // ---- epilogue: bias + Pade-gelu + w2 dot + reduce + store --------
        float b1v[4], w2v[4];
#pragma unroll
        for (int cf = 0; cf < 4; ++cf) {
            int col = c0 + wn * 64 + cf * 16 + fr;
            b1v[cf] = b1[(size_t)e * NH + col];
            w2v[cf] = w2[(size_t)e * NH + col];
        }
#pragma unroll
        for (int rf = 0; rf < 4; ++rf) {
            float pj[4] = {0.f, 0.f, 0.f, 0.f};
#pragma unroll
            for (int cf = 0; cf < 4; ++cf) {
#pragma unroll
                for (int j = 0; j < 4; ++j) {
                    float h = acc[rf][cf][j] + b1v[cf];
                    // tanh-gelu with Pade(5,4) tanh, clamped to [-1,1]
                    float u = 0.7978845608f * h * fmaf(0.044715f * h, h, 1.0f);
                    float u2 = u * u;
                    float num = u * fmaf(u2, fmaf(u2, 1.0f, 105.0f), 945.0f);
                    float den = fmaf(u2, fmaf(u2, 15.0f, 420.0f), 945.0f);
                    float t = num * __builtin_amdgcn_rcpf(den);
                    t = fminf(fmaxf(t, -1.0f), 1.0f);
                    pj[j] = fmaf(0.5f * h * (1.0f + t), w2v[cf], pj[j]);
                }
            }
#pragma unroll
            for (int m = 1; m < 16; m <<= 1)
#pragma unroll
                for (int j = 0; j < 4; ++j) pj[j] += __shfl_xor(pj[j], m);
            if ((lane & 15) == 0) {
#pragma unroll
                for (int j = 0; j < 4; ++j) {
                    int rloc = wm * 64 + rf * 16 + g * 4 + j;
                    if (rbase + rloc < cnt)
                        part[(size_t)(sbase + rloc) * NPW + ch * 2 + wn] = pj[j];
                }
            }
        }
    }
}

// ---------------- Kernel F: finalize logits (sum 32 partials + b2) --------
__global__ __launch_bounds__(256) void finalize_kernel(
    const float* __restrict__ part, const int* __restrict__ rowof,
    const int* __restrict__ idx_ws, const float* __restrict__ b2,
    float* __restrict__ logits)
{
    int s = blockIdx.x * 256 + threadIdx.x;
    const f4v* p = reinterpret_cast<const f4v*>(part + (size_t)s * NPW);
    float sum = 0.f;
#pragma unroll
    for (int i = 0; i < 8; ++i) {
        f4v v = p[i];
        sum += (v[0] + v[1]) + (v[2] + v[3]);
    }
    int row = rowof[s];
    logits[row] = sum + b2[idx_ws[row]];
}

extern "C" void kernel_launch(void* const* d_in, const int* in_sizes, int n_in,
                              void* d_out, int out_size, void* d_ws, size_t ws_size,
                              hipStream_t stream) {
    const float* z    = (const float*)d_in[0];
    const float* gw   = (const float*)d_in[1];
    const float* gb   = (const float*)d_in[2];
    const float* ln_s = (const float*)d_in[3];
    const float* ln_b = (const float*)d_in[4];
    const float* w1   = (const float*)d_in[5];
    const float* b1   = (const float*)d_in[6];
    const float* w2   = (const float*)d_in[7];
    const float* b2   = (const float*)d_in[8];

    float* logits = (float*)d_out;            // [NB]
    float* g_out  = (float*)d_out + NB;       // [NB, NE]

    char* ws = (char*)d_ws;
    unsigned short* w1t = (unsigned short*)(ws + WS_W1T_OFF);
    unsigned short* xn  = (unsigned short*)(ws + WS_XN_OFF);
    unsigned short* xns = (unsigned short*)(ws + WS_XNS_OFF);
    float* part  = (float*)(ws + WS_PART_OFF);
    int* idx_ws  = (int*)(ws + WS_IDX_OFF);
    int* rowof   = (int*)(ws + WS_ROWOF_OFF);
    int* cnts    = (int*)(ws + WS_CNT_OFF);
    int* rowl    = (int*)(ws + WS_ROWS_OFF);

    gate_w1_kernel<<<NB / 4 + NE * 64, 256, 0, stream>>>(
        z, gw, gb, ln_s, ln_b, w1, w1t, xn, idx_ws, g_out);
    bucket_kernel<<<NE, 256, 0, stream>>>(idx_ws, cnts, rowl);
    gather_kernel<<<NB / 4, 256, 0, stream>>>(xn, cnts, rowl, xns, rowof);
    mfma_mlp<<<2048, 256, 0, stream>>>(xns, w1t, b1, w2, cnts, part);
    finalize_kernel<<<NB / 256, 256, 0, stream>>>(part, rowof, idx_ws, b2,
                                                  logits);
}